// Round 4
// baseline (1595.125 us; speedup 1.0000x reference)
//
#include <hip/hip_runtime.h>
#include <cstdint>

// Problem constants
constexpr int Cc = 95;    // input channels
constexpr int Hh = 128;   // hidden
constexpr int G  = 512;   // 4*H gates
constexpr int Bb = 256;   // batch
constexpr int Tt = 1000;  // timesteps
#define EPSBN 1e-5f

typedef _Float16 half2v __attribute__((ext_vector_type(2)));

// cvt_pkrtz returns __fp16x2 on hipcc; bit_cast to the _Float16x2 the fdot2
// builtin wants (identical IEEE-half bit layout).
__device__ __forceinline__ half2v pkrtz(float a, float b) {
  return __builtin_bit_cast(half2v, __builtin_amdgcn_cvt_pkrtz(a, b));
}
__device__ __forceinline__ half2v bch(unsigned u) {
  return __builtin_bit_cast(half2v, u);
}

__device__ __forceinline__ float fdot2(half2v a, half2v b, float c) {
#if __has_builtin(__builtin_amdgcn_fdot2)
  return __builtin_amdgcn_fdot2(a, b, c, false);
#else
  return fmaf((float)a[0], (float)b[0], fmaf((float)a[1], (float)b[1], c));
#endif
}

// ---------------------------------------------------------------------------
// K1: xw[m][g] = BN(x[b, t0+tl, :]) . W_ih[g, :] + (b_ih[g] + b_hh[g])
//     f16-pair inputs, fp32 accumulate via v_dot2. K=95 -> 48 pairs.
//     LDS rows padded to 52 dwords (16B-aligned) for ds_read_b128;
//     W columns XOR-swizzled per row-quad to cut stride-4-row bank conflicts.
// ---------------------------------------------------------------------------
template <int TC>
__global__ __launch_bounds__(256)
void k1_gemm(const float* __restrict__ x, const float* __restrict__ gamma,
             const float* __restrict__ beta, const float* __restrict__ rmean,
             const float* __restrict__ rvar, const float* __restrict__ W_ih,
             const float* __restrict__ b_ih, const float* __restrict__ b_hh,
             float* __restrict__ xw, int t0) {
  constexpr int KP = 48;   // ceil(95/2)
  constexpr int LD = 52;   // row stride in half2v (208 B, 16B-aligned)
  __shared__ __align__(16) half2v As2[64][LD];
  __shared__ __align__(16) half2v Ws2[64][LD];
  __shared__ float scl[Cc], sft[Cc];

  const int tid = threadIdx.x;
  if (tid < Cc) {
    float s = gamma[tid] * rsqrtf(rvar[tid] + EPSBN);
    scl[tid] = s;
    sft[tid] = beta[tid] - rmean[tid] * s;
  }
  __syncthreads();

  const int row0 = blockIdx.x * 64;  // chunk-local xn row
  const int col0 = blockIdx.y * 64;  // gate column

  for (int idx = tid; idx < 64 * KP; idx += 256) {
    int r = idx / KP;
    int kp = idx - r * KP;
    int c0 = 2 * kp;
    int m = row0 + r;
    int b = m / TC;
    int tl = m - b * TC;
    const float* xr = x + ((size_t)b * Tt + t0 + tl) * Cc;
    float a0 = xr[c0] * scl[c0] + sft[c0];
    float a1 = (c0 + 1 < Cc) ? xr[c0 + 1] * scl[c0 + 1] + sft[c0 + 1] : 0.f;
    As2[r][kp] = pkrtz(a0, a1);
    const float* wr = W_ih + (size_t)(col0 + r) * Cc;
    float w0 = wr[c0];
    float w1 = (c0 + 1 < Cc) ? wr[c0 + 1] : 0.f;
    // swizzle: flip kp bits 2-3 by row-quad id (keeps value < 48)
    Ws2[r][kp ^ (((r >> 2) & 3) << 2)] = pkrtz(w0, w1);
  }
  __syncthreads();

  const int tx = tid & 15, ty = tid >> 4;
  const int ai = ty * 4, wi = tx * 4;
  const int swz = (tx & 3) << 2;  // == (((wi+i)>>2)&3)<<2 for i in 0..3
  float acc[4][4] = {};

#pragma unroll
  for (int kb = 0; kb < KP; kb += 4) {
    uint4 av[4], wv[4];
#pragma unroll
    for (int i = 0; i < 4; ++i) {
      av[i] = *reinterpret_cast<const uint4*>(&As2[ai + i][kb]);
      wv[i] = *reinterpret_cast<const uint4*>(&Ws2[wi + i][kb ^ swz]);
    }
#pragma unroll
    for (int i = 0; i < 4; ++i)
#pragma unroll
      for (int jx = 0; jx < 4; ++jx) {
        float a = acc[i][jx];
        a = fdot2(bch(av[i].x), bch(wv[jx].x), a);
        a = fdot2(bch(av[i].y), bch(wv[jx].y), a);
        a = fdot2(bch(av[i].z), bch(wv[jx].z), a);
        a = fdot2(bch(av[i].w), bch(wv[jx].w), a);
        acc[i][jx] = a;
      }
  }

  float bi0 = b_ih[col0 + wi + 0] + b_hh[col0 + wi + 0];
  float bi1 = b_ih[col0 + wi + 1] + b_hh[col0 + wi + 1];
  float bi2 = b_ih[col0 + wi + 2] + b_hh[col0 + wi + 2];
  float bi3 = b_ih[col0 + wi + 3] + b_hh[col0 + wi + 3];
#pragma unroll
  for (int i = 0; i < 4; ++i) {
    size_t m = (size_t)(row0 + ai + i);
    float4 v = make_float4(acc[i][0] + bi0, acc[i][1] + bi1,
                           acc[i][2] + bi2, acc[i][3] + bi3);
    *reinterpret_cast<float4*>(&xw[m * G + col0 + wi]) = v;
  }
}

// ---------------------------------------------------------------------------
// K2: per-batch LSTM recurrence, TWO batch elements per block (1024 threads,
// grid 128) -> 4 waves/SIMD co-resident so independent chains fill the
// latency stalls of the serial recurrence.
// Within a 512-thread sub-block: tid = 4*j + q, unit j, gate q (i,f,g,o).
// Gates of a unit in adjacent lanes -> i/f/g/o exchange via shfl_xor.
// h packed-f16, double-buffered LDS -> ONE barrier per step.
// ---------------------------------------------------------------------------
template <int TC>
__global__ __launch_bounds__(1024)
void k2_lstm(const float* __restrict__ xw, const float* __restrict__ W_hh,
             float* __restrict__ hstate, float* __restrict__ cstate,
             const float* __restrict__ fc_w, const float* __restrict__ fc_b,
             float* __restrict__ out, int t0) {
  __shared__ __align__(16) half2v h2lds[2][2][Hh / 2];  // [sub][buf][pair]
  __shared__ float h32[2][Hh];

  const int tid = threadIdx.x;
  const int sub = tid >> 9;            // which batch element of the pair
  const int g = tid & 511;
  const int b = blockIdx.x * 2 + sub;
  const int j = g >> 2;                // hidden unit
  const int q = g & 3;                 // gate type (torch order i,f,g,o)
  const int r = q * Hh + j;            // gate-row index
  const bool isg = (q == 2);           // tanh gate

  // W_hh row -> packed f16 pairs in registers (256 KB total, L2-resident)
  half2v w2[64];
  {
    const float2* wr = reinterpret_cast<const float2*>(W_hh + (size_t)r * Hh);
#pragma unroll
    for (int i = 0; i < 64; ++i) {
      float2 t = wr[i];
      w2[i] = pkrtz(t.x, t.y);
    }
  }

  float creg = 0.f, hreg = 0.f;
  if (t0 == 0) {
    if (g < Hh / 2) h2lds[sub][0][g] = half2v{(_Float16)0, (_Float16)0};
  } else {
    if (q == 0) {
      hreg = hstate[b * Hh + j];
      creg = cstate[b * Hh + j];
    }
    if (g < Hh / 2)
      h2lds[sub][0][g] = pkrtz(hstate[b * Hh + 2 * g],
                               hstate[b * Hh + 2 * g + 1]);
  }
  __syncthreads();

  const float* xwb = xw + (size_t)b * TC * G;
  float xw_cur = xwb[r];
  float xw_nxt = (TC > 1) ? xwb[G + r] : 0.f;

  for (int tl = 0; tl < TC; ++tl) {
    const int rb = tl & 1;
    float xw_pre = 0.f;
    if (tl + 2 < TC) xw_pre = xwb[(size_t)(tl + 2) * G + r];

    // gate = xw + W_hh[r,:] . h   (64 dot2, 4 accumulator chains)
    float a0 = xw_cur, a1 = 0.f, a2 = 0.f, a3 = 0.f;
    const uint4* hp = reinterpret_cast<const uint4*>(h2lds[sub][rb]);
#pragma unroll
    for (int kk = 0; kk < 16; ++kk) {
      uint4 hv = hp[kk];  // broadcast read (uniform address per sub)
      a0 = fdot2(w2[4 * kk + 0], bch(hv.x), a0);
      a1 = fdot2(w2[4 * kk + 1], bch(hv.y), a1);
      a2 = fdot2(w2[4 * kk + 2], bch(hv.z), a2);
      a3 = fdot2(w2[4 * kk + 3], bch(hv.w), a3);
    }
    float gate = (a0 + a1) + (a2 + a3);

    // branchless activation: sigmoid for q!=2, tanh(x)=2*sigmoid(2x)-1 for q==2
    float y = isg ? 2.f * gate : gate;
    y = fminf(30.f, fmaxf(-30.f, y));
    float e = __expf(-y);
    float s = __fdividef(1.f, 1.f + e);
    float v = isg ? fmaf(2.f, s, -1.f) : s;

    // quad exchange within wave
    float vb = __shfl_xor(v, 1);
    float vc = __shfl_xor(v, 2);
    float vd = __shfl_xor(vb, 2);

    if (q == 0) {  // v=i, vb=f, vc=g, vd=o
      creg = fmaf(vb, creg, v * vc);
      float yc = fminf(30.f, fmaxf(-30.f, 2.f * creg));
      float ec = __expf(yc);
      float th = __fdividef(ec - 1.f, ec + 1.f);  // tanh(c)
      hreg = vd * th;
    }
    float hn = __shfl_down(hreg, 4);
    if ((g & 7) == 0)
      h2lds[sub][rb ^ 1][j >> 1] = pkrtz(hreg, hn);
    __syncthreads();  // single barrier per step (double-buffered h)

    xw_cur = xw_nxt;
    xw_nxt = xw_pre;
  }

  if (q == 0) {
    hstate[b * Hh + j] = hreg;
    cstate[b * Hh + j] = creg;
    h32[sub][j] = hreg;
  }
  __syncthreads();

  // Final FC fused into the last chunk (256x4)
  if (t0 + TC == Tt && g < 4) {
    float s = fc_b[g];
    for (int jj = 0; jj < Hh; ++jj)
      s = fmaf(h32[sub][jj], fc_w[g * Hh + jj], s);
    out[b * 4 + g] = s;
  }
}

// ---------------------------------------------------------------------------
template <int TC>
static void run_chunks(const float* x, const float* gamma, const float* beta,
                       const float* rmean, const float* rvar,
                       const float* W_ih, const float* W_hh,
                       const float* b_ih, const float* b_hh,
                       const float* fc_w, const float* fc_b, float* out,
                       void* d_ws, hipStream_t stream) {
  float* xw = reinterpret_cast<float*>(d_ws);
  float* hst = xw + (size_t)Bb * TC * G;
  float* cst = hst + (size_t)Bb * Hh;
  for (int t0 = 0; t0 < Tt; t0 += TC) {
    dim3 g1(Bb * TC / 64, G / 64);
    k1_gemm<TC><<<g1, dim3(256), 0, stream>>>(x, gamma, beta, rmean, rvar,
                                              W_ih, b_ih, b_hh, xw, t0);
    k2_lstm<TC><<<dim3(Bb / 2), dim3(1024), 0, stream>>>(xw, W_hh, hst, cst,
                                                         fc_w, fc_b, out, t0);
  }
}

extern "C" void kernel_launch(void* const* d_in, const int* in_sizes, int n_in,
                              void* d_out, int out_size, void* d_ws,
                              size_t ws_size, hipStream_t stream) {
  const float* x     = (const float*)d_in[0];
  const float* gamma = (const float*)d_in[1];
  const float* beta  = (const float*)d_in[2];
  const float* rmean = (const float*)d_in[3];
  const float* rvar  = (const float*)d_in[4];
  const float* W_ih  = (const float*)d_in[5];
  const float* W_hh  = (const float*)d_in[6];
  const float* b_ih  = (const float*)d_in[7];
  const float* b_hh  = (const float*)d_in[8];
  const float* fc_w  = (const float*)d_in[9];
  const float* fc_b  = (const float*)d_in[10];
  float* out = (float*)d_out;

  auto need = [](int tc) {
    return (size_t)Bb * tc * G * 4 + 2 * (size_t)Bb * Hh * 4;
  };

  if (ws_size >= need(250)) {
    run_chunks<250>(x, gamma, beta, rmean, rvar, W_ih, W_hh, b_ih, b_hh, fc_w,
                    fc_b, out, d_ws, stream);
  } else if (ws_size >= need(125)) {
    run_chunks<125>(x, gamma, beta, rmean, rvar, W_ih, W_hh, b_ih, b_hh, fc_w,
                    fc_b, out, d_ws, stream);
  } else if (ws_size >= need(50)) {
    run_chunks<50>(x, gamma, beta, rmean, rvar, W_ih, W_hh, b_ih, b_hh, fc_w,
                   fc_b, out, d_ws, stream);
  } else {
    run_chunks<10>(x, gamma, beta, rmean, rvar, W_ih, W_hh, b_ih, b_hh, fc_w,
                   fc_b, out, d_ws, stream);
  }
}

// Round 5
// 853.200 us; speedup vs baseline: 1.8696x; 1.8696x over previous
//
#include <hip/hip_runtime.h>
#include <cstdint>

// Problem constants
constexpr int Cc = 95;    // input channels
constexpr int Hh = 128;   // hidden
constexpr int G  = 512;   // 4*H gates
constexpr int Bb = 256;   // batch
constexpr int Tt = 1000;  // timesteps
#define EPSBN 1e-5f

typedef _Float16 half2v __attribute__((ext_vector_type(2)));
typedef _Float16 half8  __attribute__((ext_vector_type(8)));
typedef float floatx4 __attribute__((ext_vector_type(4)));
typedef float float4u __attribute__((ext_vector_type(4), aligned(4)));
typedef float float2u __attribute__((ext_vector_type(2), aligned(4)));

__device__ __forceinline__ half2v pkrtz(float a, float b) {
  return __builtin_bit_cast(half2v, __builtin_amdgcn_cvt_pkrtz(a, b));
}
__device__ __forceinline__ unsigned pku(float a, float b) {
  return __builtin_bit_cast(unsigned, __builtin_amdgcn_cvt_pkrtz(a, b));
}
__device__ __forceinline__ half2v bch(unsigned u) {
  return __builtin_bit_cast(half2v, u);
}
__device__ __forceinline__ float fdot2(half2v a, half2v b, float c) {
#if __has_builtin(__builtin_amdgcn_fdot2)
  return __builtin_amdgcn_fdot2(a, b, c, false);
#else
  return fmaf((float)a[0], (float)b[0], fmaf((float)a[1], (float)b[1], c));
#endif
}

// ---------------------------------------------------------------------------
// K0 (once per launch): fold BN into W_ih -> Wp f16 [512][96] (k=95 padded 0),
// bias'[g] = b_ih+b_hh + sum_c sft_c * W_ih[g][c].
// ---------------------------------------------------------------------------
__global__ __launch_bounds__(512)
void k0_prep(const float* __restrict__ gamma, const float* __restrict__ beta,
             const float* __restrict__ rmean, const float* __restrict__ rvar,
             const float* __restrict__ W_ih, const float* __restrict__ b_ih,
             const float* __restrict__ b_hh, float* __restrict__ biasp,
             _Float16* __restrict__ Wp) {
  __shared__ float scl[Cc], sft[Cc];
  const int t = threadIdx.x;
  if (t < Cc) {
    float s = gamma[t] * rsqrtf(rvar[t] + EPSBN);
    scl[t] = s;
    sft[t] = beta[t] - rmean[t] * s;
  }
  __syncthreads();
  // t = gate row
  float acc = b_ih[t] + b_hh[t];
  const float* wr = W_ih + (size_t)t * Cc;
  for (int c = 0; c < Cc; ++c) {
    float w = wr[c];
    acc = fmaf(sft[c], w, acc);
    Wp[t * 96 + c] = (_Float16)(w * scl[c]);  // RNE cast
  }
  Wp[t * 96 + 95] = (_Float16)0.f;
  biasp[t] = acc;
}

// ---------------------------------------------------------------------------
// K1: xw = x_f16 . Wp^T + bias'  via mfma_f32_16x16x32_f16.
// Block: 512 thr = 8 waves (2 M x 4 N). Block tile 64 rows x 512 gates.
// Per wave: 32 rows x 128 gates = 2x8 C-tiles, K = 96 = 3 k-steps.
// A/B fragments loaded straight from global (L2-hot W; x read once).
// A layout: lane holds A[row=l&15][k=8*(l>>4)+i]; B: B[k=8*(l>>4)+i][col=l&15]
//   = Wp[col][k] (8 consecutive f16 = one dwordx4).  D: row=4*(l>>4)+r, col=l&15.
// ---------------------------------------------------------------------------
template <int TC>
__global__ __launch_bounds__(512)
void k1_mfma(const float* __restrict__ x, const _Float16* __restrict__ Wp,
             const float* __restrict__ biasp, float* __restrict__ xw, int t0) {
  const int tid = threadIdx.x;
  const int wave = tid >> 6, lane = tid & 63;
  const int wm = wave >> 2, wn = wave & 3;
  const int row0 = blockIdx.x * 64 + wm * 32;  // chunk-local row base
  const int nb0 = wn * 128;                    // gate col base
  const int l15 = lane & 15, lg = lane >> 4;

  // A fragments: [mt][kk], each 8 f16 from one x row (raw x, BN folded into W)
  uint4 afr[2][3];
#pragma unroll
  for (int mt = 0; mt < 2; ++mt) {
    int m = row0 + mt * 16 + l15;
    int b = m / TC, tl = m - b * TC;
    const float* xr = x + ((size_t)b * Tt + t0 + tl) * Cc;
#pragma unroll
    for (int kk = 0; kk < 3; ++kk) {
      int k = kk * 32 + lg * 8;
      float4u p0 = *reinterpret_cast<const float4u*>(xr + k);
      float e4, e5, e6, e7;
      if (k == 88) {  // tail: k..k+7 = 88..95; elem 95 is pad (Wp col 95 = 0)
        float2u q = *reinterpret_cast<const float2u*>(xr + 92);
        e4 = q[0]; e5 = q[1]; e6 = xr[94]; e7 = 0.f;
      } else {
        float4u p1 = *reinterpret_cast<const float4u*>(xr + k + 4);
        e4 = p1[0]; e5 = p1[1]; e6 = p1[2]; e7 = p1[3];
      }
      afr[mt][kk] = make_uint4(pku(p0[0], p0[1]), pku(p0[2], p0[3]),
                               pku(e4, e5), pku(e6, e7));
    }
  }

  floatx4 acc[2][8] = {};
#pragma unroll
  for (int nt = 0; nt < 8; ++nt) {
    const _Float16* wrow = Wp + (size_t)(nb0 + nt * 16 + l15) * 96 + lg * 8;
#pragma unroll
    for (int kk = 0; kk < 3; ++kk) {
      uint4 bfr = *reinterpret_cast<const uint4*>(wrow + kk * 32);
      half8 bv = __builtin_bit_cast(half8, bfr);
      acc[0][nt] = __builtin_amdgcn_mfma_f32_16x16x32_f16(
          __builtin_bit_cast(half8, afr[0][kk]), bv, acc[0][nt], 0, 0, 0);
      acc[1][nt] = __builtin_amdgcn_mfma_f32_16x16x32_f16(
          __builtin_bit_cast(half8, afr[1][kk]), bv, acc[1][nt], 0, 0, 0);
    }
  }

#pragma unroll
  for (int nt = 0; nt < 8; ++nt) {
    int n = nb0 + nt * 16 + l15;
    float bias = biasp[n];
#pragma unroll
    for (int mt = 0; mt < 2; ++mt) {
      int rbase = row0 + mt * 16 + lg * 4;
#pragma unroll
      for (int r = 0; r < 4; ++r)
        xw[(size_t)(rbase + r) * G + n] = acc[mt][nt][r] + bias;
    }
  }
}

// ---------------------------------------------------------------------------
// K2: per-batch LSTM recurrence. 256 blocks x 256 threads (4 waves).
// tid = 2*j + p: unit j in [0,128); p=0 -> rows {i:j, f:128+j},
//                                   p=1 -> rows {g:256+j, o:384+j}.
// Each thread: 2 gate rows => 2x64 f16-pair weights (128 VGPR), 8 dot chains.
// i/g and f/o exchanged via shfl_xor(1). h packed-f16, double-buffered LDS,
// ONE barrier per step. __launch_bounds__(256,1) -> VGPR cap 512, no spill.
// ---------------------------------------------------------------------------
template <int TC>
__global__ __launch_bounds__(256, 1)
void k2_lstm(const float* __restrict__ xw, const float* __restrict__ W_hh,
             float* __restrict__ hstate, float* __restrict__ cstate,
             const float* __restrict__ fc_w, const float* __restrict__ fc_b,
             float* __restrict__ out, int t0) {
  __shared__ __align__(16) half2v h2lds[2][Hh / 2];
  __shared__ float h32[Hh];

  const int b = blockIdx.x;
  const int t = threadIdx.x;
  const int j = t >> 1;   // hidden unit
  const int p = t & 1;    // row-pair selector
  const int r0 = p ? 2 * Hh + j : j;        // g-row : i-row
  const int r1 = p ? 3 * Hh + j : Hh + j;   // o-row : f-row

  // two W_hh rows -> packed f16 pairs in registers
  half2v wa[64], wb[64];
  {
    const float2* wr0 = reinterpret_cast<const float2*>(W_hh + (size_t)r0 * Hh);
    const float2* wr1 = reinterpret_cast<const float2*>(W_hh + (size_t)r1 * Hh);
#pragma unroll
    for (int i = 0; i < 64; ++i) {
      float2 u = wr0[i]; wa[i] = pkrtz(u.x, u.y);
      float2 v = wr1[i]; wb[i] = pkrtz(v.x, v.y);
    }
  }

  float creg = 0.f, hreg = 0.f;
  if (t0 == 0) {
    if (t < Hh / 2) h2lds[0][t] = half2v{(_Float16)0, (_Float16)0};
  } else {
    if (p == 0) {
      hreg = hstate[b * Hh + j];
      creg = cstate[b * Hh + j];
    }
    if (t < Hh / 2)
      h2lds[0][t] = pkrtz(hstate[b * Hh + 2 * t], hstate[b * Hh + 2 * t + 1]);
  }
  __syncthreads();

  const float* xwb = xw + (size_t)b * TC * G;
  float cur0 = xwb[r0], cur1 = xwb[r1];
  float nxt0 = (TC > 1) ? xwb[G + r0] : 0.f;
  float nxt1 = (TC > 1) ? xwb[G + r1] : 0.f;

  for (int tl = 0; tl < TC; ++tl) {
    const int rb = tl & 1;
    float pre0 = 0.f, pre1 = 0.f;
    if (tl + 2 < TC) {
      pre0 = xwb[(size_t)(tl + 2) * G + r0];
      pre1 = xwb[(size_t)(tl + 2) * G + r1];
    }

    // two gate dots, 8 accumulator chains
    float a0 = cur0, a1 = 0.f, a2 = 0.f, a3 = 0.f;
    float c0 = cur1, c1 = 0.f, c2 = 0.f, c3 = 0.f;
    const uint4* hp = reinterpret_cast<const uint4*>(h2lds[rb]);
#pragma unroll
    for (int kk = 0; kk < 16; ++kk) {
      uint4 hv = hp[kk];  // uniform address -> broadcast
      a0 = fdot2(wa[4 * kk + 0], bch(hv.x), a0);
      a1 = fdot2(wa[4 * kk + 1], bch(hv.y), a1);
      a2 = fdot2(wa[4 * kk + 2], bch(hv.z), a2);
      a3 = fdot2(wa[4 * kk + 3], bch(hv.w), a3);
      c0 = fdot2(wb[4 * kk + 0], bch(hv.x), c0);
      c1 = fdot2(wb[4 * kk + 1], bch(hv.y), c1);
      c2 = fdot2(wb[4 * kk + 2], bch(hv.z), c2);
      c3 = fdot2(wb[4 * kk + 3], bch(hv.w), c3);
    }
    float g0 = (a0 + a1) + (a2 + a3);  // i (p0) / g (p1)
    float g1 = (c0 + c1) + (c2 + c3);  // f (p0) / o (p1)

    // activations: g0 -> sigmoid (p0) or tanh (p1); g1 -> sigmoid always
    float y0 = p ? 2.f * g0 : g0;
    y0 = fminf(30.f, fmaxf(-30.f, y0));
    float e0 = __expf(-y0);
    float s0 = __fdividef(1.f, 1.f + e0);
    float v0 = p ? fmaf(2.f, s0, -1.f) : s0;

    float y1 = fminf(30.f, fmaxf(-30.f, g1));
    float e1 = __expf(-y1);
    float v1 = __fdividef(1.f, 1.f + e1);

    float u0 = __shfl_xor(v0, 1);  // p0 gets g
    float u1 = __shfl_xor(v1, 1);  // p0 gets o

    if (p == 0) {  // v0=i, v1=f, u0=g, u1=o
      creg = fmaf(v1, creg, v0 * u0);
      float yc = fminf(30.f, fmaxf(-30.f, 2.f * creg));
      float ec = __expf(yc);
      float th = __fdividef(ec - 1.f, ec + 1.f);  // tanh(c)
      hreg = u1 * th;
    }
    float hn = __shfl_down(hreg, 2);  // h_{j+1} from thread t+2
    if ((t & 3) == 0)
      h2lds[rb ^ 1][t >> 2] = pkrtz(hreg, hn);
    __syncthreads();  // single barrier per step

    cur0 = nxt0; cur1 = nxt1;
    nxt0 = pre0; nxt1 = pre1;
  }

  if (p == 0) {
    hstate[b * Hh + j] = hreg;
    cstate[b * Hh + j] = creg;
    h32[j] = hreg;
  }
  __syncthreads();

  if (t0 + TC == Tt && t < 4) {
    float s = fc_b[t];
    for (int jj = 0; jj < Hh; ++jj) s = fmaf(h32[jj], fc_w[t * Hh + jj], s);
    out[b * 4 + t] = s;
  }
}

// ---------------------------------------------------------------------------
template <int TC>
static void run_chunks(const float* x, const float* gamma, const float* beta,
                       const float* rmean, const float* rvar,
                       const float* W_ih, const float* W_hh,
                       const float* b_ih, const float* b_hh,
                       const float* fc_w, const float* fc_b, float* out,
                       void* d_ws, hipStream_t stream) {
  char* ws = reinterpret_cast<char*>(d_ws);
  float* xwp  = reinterpret_cast<float*>(ws);
  size_t off  = (size_t)Bb * TC * G * 4;
  float* hst  = reinterpret_cast<float*>(ws + off);  off += (size_t)Bb * Hh * 4;
  float* cst  = reinterpret_cast<float*>(ws + off);  off += (size_t)Bb * Hh * 4;
  float* bia  = reinterpret_cast<float*>(ws + off);  off += 512 * 4;
  off = (off + 15) & ~(size_t)15;
  _Float16* Wp = reinterpret_cast<_Float16*>(ws + off);

  k0_prep<<<dim3(1), dim3(512), 0, stream>>>(gamma, beta, rmean, rvar, W_ih,
                                             b_ih, b_hh, bia, Wp);
  for (int t0 = 0; t0 < Tt; t0 += TC) {
    k1_mfma<TC><<<dim3(Bb * TC / 64), dim3(512), 0, stream>>>(x, Wp, bia, xwp,
                                                              t0);
    k2_lstm<TC><<<dim3(Bb), dim3(256), 0, stream>>>(xwp, W_hh, hst, cst, fc_w,
                                                    fc_b, out, t0);
  }
}

extern "C" void kernel_launch(void* const* d_in, const int* in_sizes, int n_in,
                              void* d_out, int out_size, void* d_ws,
                              size_t ws_size, hipStream_t stream) {
  const float* x     = (const float*)d_in[0];
  const float* gamma = (const float*)d_in[1];
  const float* beta  = (const float*)d_in[2];
  const float* rmean = (const float*)d_in[3];
  const float* rvar  = (const float*)d_in[4];
  const float* W_ih  = (const float*)d_in[5];
  const float* W_hh  = (const float*)d_in[6];
  const float* b_ih  = (const float*)d_in[7];
  const float* b_hh  = (const float*)d_in[8];
  const float* fc_w  = (const float*)d_in[9];
  const float* fc_b  = (const float*)d_in[10];
  float* out = (float*)d_out;

  auto need = [](int tc) {
    return (size_t)Bb * tc * G * 4 + 2 * (size_t)Bb * Hh * 4 + 512 * 4 + 16 +
           (size_t)512 * 96 * 2;
  };

  if (ws_size >= need(1000)) {
    run_chunks<1000>(x, gamma, beta, rmean, rvar, W_ih, W_hh, b_ih, b_hh, fc_w,
                     fc_b, out, d_ws, stream);
  } else if (ws_size >= need(500)) {
    run_chunks<500>(x, gamma, beta, rmean, rvar, W_ih, W_hh, b_ih, b_hh, fc_w,
                    fc_b, out, d_ws, stream);
  } else if (ws_size >= need(250)) {
    run_chunks<250>(x, gamma, beta, rmean, rvar, W_ih, W_hh, b_ih, b_hh, fc_w,
                    fc_b, out, d_ws, stream);
  } else if (ws_size >= need(125)) {
    run_chunks<125>(x, gamma, beta, rmean, rvar, W_ih, W_hh, b_ih, b_hh, fc_w,
                    fc_b, out, d_ws, stream);
  } else if (ws_size >= need(50)) {
    run_chunks<50>(x, gamma, beta, rmean, rvar, W_ih, W_hh, b_ih, b_hh, fc_w,
                   fc_b, out, d_ws, stream);
  } else {
    run_chunks<10>(x, gamma, beta, rmean, rvar, W_ih, W_hh, b_ih, b_hh, fc_w,
                   fc_b, out, d_ws, stream);
  }
}